// Round 4
// baseline (827.209 us; speedup 1.0000x reference)
//
#include <hip/hip_runtime.h>
#include <math.h>

// Problem constants (from reference)
#define VOC 50000
#define DIM 128
#define B   256
#define CTX 8
#define K   10

#define NVEC (VOC / 4)          // 12500 float4 per one-hot row
#define NSTEP ((NVEC + 255) / 256)   // 49 steps of 256 vec4 (1024 floats)
#define N_VO  (B)               // 256 rows
#define N_VI  (B * CTX)         // 2048 rows
#define N_NEG (B * K)           // 2560 rows
#define NROW  (N_VO + N_VI + N_NEG)  // 4864 rows

#define ROWS_PER_BLOCK 4        // 4 independent waves per block, 1 row each

typedef float f32x4 __attribute__((ext_vector_type(4)));

// ---------------------------------------------------------------------------
// Kernel 1: find the index of the single nonzero in each one-hot row.
// One WAVE per row, forward scan, 4 KB/step, ballot early-exit — PLUS
// depth-1 speculative pipelining: step s+1's loads are issued BEFORE step
// s's values are consumed, so the compare/ballot/branch chain no longer
// sits inside the HBM round trip (compiler emits s_waitcnt vmcnt(4),
// leaving the prefetch in flight across the wave-uniform branch).
// Cost: one wasted 4 KB step per row (+20 MB ≈ +4 us if BW-bound);
// exit granularity stays 4 KB. Expected read ~497 MB (information floor
// for adaptive search = half the 973 MB one-hot data).
// r2 lesson: bidirectional scan (4x granularity waste) ~neutral; this
// isolates the chain-latency mechanism with bounded waste.
// Also zeroes out[0] (stream-ordered before cbow_loss's atomics).
// ---------------------------------------------------------------------------
__global__ __launch_bounds__(256) void find_indices(
    const float* __restrict__ vo,
    const float* __restrict__ vi,
    const float* __restrict__ neg,
    int* __restrict__ out_idx,
    float* __restrict__ out)
{
    if (blockIdx.x == 0 && threadIdx.x == 0) out[0] = 0.f;  // replaces memset

    const int wave = threadIdx.x >> 6;     // 0..3
    const int lane = threadIdx.x & 63;     // 0..63
    const int r = blockIdx.x * ROWS_PER_BLOCK + wave;   // grid exact: 1216*4 == NROW

    const float* row;
    if (r < N_VO)              row = vo  + (size_t)r * VOC;
    else if (r < N_VO + N_VI)  row = vi  + (size_t)(r - N_VO) * VOC;
    else                       row = neg + (size_t)(r - N_VO - N_VI) * VOC;

    const f32x4* row4 = (const f32x4*)row;

    // Prologue: load step 0 into cur.
    f32x4 cur[4];
#pragma unroll
    for (int j = 0; j < 4; ++j) {
        const int p = j * 64 + lane;           // < 256 < NVEC, no clamp needed
        cur[j] = __builtin_nontemporal_load(&row4[p]);
    }

    for (int s = 0; s < NSTEP; ++s) {
        const int base = s * 256;

        // Speculative prefetch of step s+1 — issued before cur is consumed.
        // Final step: all indices clamp to NVEC-1 (one dup 64B line, benign).
        f32x4 nxt[4];
#pragma unroll
        for (int j = 0; j < 4; ++j) {
            int p = base + 256 + j * 64 + lane;
            p = (p < NVEC) ? p : (NVEC - 1);
            nxt[j] = __builtin_nontemporal_load(&row4[p]);
        }

        // Check cur. Static indexing only (runtime-indexed ext_vector arrays
        // go to scratch): capture value+index inside the unrolled loop.
        int   myp = -1;
        f32x4 mv  = cur[0];
#pragma unroll
        for (int j = 3; j >= 0; --j) {         // descending so smallest j wins
            const f32x4 a = cur[j];
            if (a.x != 0.f || a.y != 0.f || a.z != 0.f || a.w != 0.f) {
                int p = base + j * 64 + lane;
                myp = (p < NVEC) ? p : (NVEC - 1);
                mv  = a;
            }
        }

        const unsigned long long m = __ballot(myp >= 0);
        if (m != 0ull) {                       // wave-uniform branch
            if (lane == __ffsll(m) - 1) {      // exactly one writer
                const int off = (mv.x != 0.f) ? 0 : (mv.y != 0.f) ? 1
                              : (mv.z != 0.f) ? 2 : 3;
                out_idx[r] = 4 * myp + off;
            }
            break;
        }

#pragma unroll
        for (int j = 0; j < 4; ++j) cur[j] = nxt[j];   // static rotate
    }
    // one-hot guaranteed by setup => always found; loss kernel clamps anyway.
}

// ---------------------------------------------------------------------------
// Kernel 2: per-batch-row loss. One wave per b; thread t owns dims {2t,2t+1}
// via float2 gathers. 11 wave-shuffle dot reductions, then one atomicAdd of
// -(left+right)/B into out[0].
// ---------------------------------------------------------------------------
__device__ __forceinline__ float wave_sum(float v) {
#pragma unroll
    for (int o = 32; o > 0; o >>= 1) v += __shfl_down(v, o);
    return v;   // valid in lane 0
}

__device__ __forceinline__ float log_sigmoid(float x) {
    // stable: min(x,0) - log1p(exp(-|x|))
    return fminf(x, 0.f) - log1pf(expf(-fabsf(x)));
}

__device__ __forceinline__ int clamp_idx(int i) {
    // idx workspace is never zeroed (harness poisons it) — clamp defensively
    // so a pathological unwritten slot can't cause an OOB gather.
    return i < 0 ? 0 : (i >= VOC ? VOC - 1 : i);
}

__global__ __launch_bounds__(64) void cbow_loss(
    const float* __restrict__ V,
    const float* __restrict__ U,
    const int* __restrict__ idx_all,
    float* __restrict__ out)
{
    const int b = blockIdx.x;     // 0..255
    const int t = threadIdx.x;    // 0..63

    const int* idx_vo  = idx_all;
    const int* idx_vi  = idx_all + N_VO;
    const int* idx_neg = idx_all + N_VO + N_VI;

    const int vo_i = clamp_idx(idx_vo[b]);
    const float2 v = ((const float2*)(V + (size_t)vo_i * DIM))[t];

    float2 e = make_float2(0.f, 0.f);
#pragma unroll
    for (int c = 0; c < CTX; ++c) {
        const int u = clamp_idx(idx_vi[b * CTX + c]);
        const float2 uu = ((const float2*)(U + (size_t)u * DIM))[t];
        e.x += uu.x;
        e.y += uu.y;
    }
    e.x *= (1.f / CTX);
    e.y *= (1.f / CTX);

    const float dot_pos = wave_sum(v.x * e.x + v.y * e.y);

    float right = 0.f;
#pragma unroll
    for (int k = 0; k < K; ++k) {
        const int u = clamp_idx(idx_neg[b * K + k]);
        const float2 uu = ((const float2*)(U + (size_t)u * DIM))[t];
        const float s = wave_sum(v.x * uu.x + v.y * uu.y);
        if (t == 0) right += log_sigmoid(-s);
    }

    if (t == 0) {
        const float left = log_sigmoid(dot_pos);
        atomicAdd(out, -(left + right) * (1.f / B));
    }
}

// ---------------------------------------------------------------------------
// Launch
// ---------------------------------------------------------------------------
extern "C" void kernel_launch(void* const* d_in, const int* in_sizes, int n_in,
                              void* d_out, int out_size, void* d_ws, size_t ws_size,
                              hipStream_t stream) {
    const float* vo  = (const float*)d_in[0];   // [B, VOC]
    const float* vi  = (const float*)d_in[1];   // [B, CTX, VOC]
    const float* neg = (const float*)d_in[2];   // [B, K, VOC]
    const float* V   = (const float*)d_in[3];   // [VOC, DIM]
    const float* U   = (const float*)d_in[4];   // [VOC, DIM]
    float* out = (float*)d_out;

    int* idx_ws = (int*)d_ws;                   // NROW ints = 19456 B

    // out[0] is zeroed by find_indices (stream-ordered before cbow_loss's
    // atomics) — no separate memset dispatch needed.
    find_indices<<<NROW / ROWS_PER_BLOCK, 256, 0, stream>>>(vo, vi, neg, idx_ws, out);
    cbow_loss<<<B, 64, 0, stream>>>(V, U, idx_ws, out);
}